// Round 20
// baseline (169.197 us; speedup 1.0000x reference)
//
#include <hip/hip_runtime.h>
#include <math.h>

// DifferentiableMultiMLPRenderer — round 20: r19 renderer (unchanged) + pgemm
// with swapped-operand MFMA (vectorized 8B P-stores, was 64 scalar 2B stores)
// and launch_bounds(256,3): 768 resident blocks >= 782 grid -> single round.

typedef _Float16 hv8 __attribute__((ext_vector_type(8)));
typedef _Float16 hv4 __attribute__((ext_vector_type(4)));
typedef __attribute__((ext_vector_type(4))) float f32x4;

#define TILE_M 64

__device__ inline int swzE(int row, int k) { return row * 64  + (k ^ ((row & 7) << 3)); }
__device__ inline int swzH(int row, int k) { return row * 256 + (k ^ ((row & 7) << 3)); }
__device__ inline int swzA(int row, int k) { return row * 384 + (k ^ ((row & 7) << 3)); }

// ---- prep: fold style into b1; build f16 weights: w1T (1/3 folded), w2T, w3T ----
__global__ __launch_bounds__(256)
void prep_weights(const float* __restrict__ style,
                  const float* __restrict__ w1, const float* __restrict__ b1,
                  const float* __restrict__ w2, const float* __restrict__ w3,
                  _Float16* __restrict__ w1T, _Float16* __restrict__ w2T,
                  _Float16* __restrict__ w3T, float* __restrict__ b1p)
{
    const int j = blockIdx.x;
    const int t = threadIdx.x;
    if (j < 256) {
        float part = style[t] * w1[(size_t)(447 + t) * 256 + j];
        #pragma unroll
        for (int off = 32; off; off >>= 1) part += __shfl_down(part, off, 64);
        __shared__ float red[4];
        if ((t & 63) == 0) red[t >> 6] = part;
        __syncthreads();
        if (t == 0) b1p[j] = b1[j] + red[0] + red[1] + red[2] + red[3];
        for (int k = t; k < 448; k += 256) {
            float v = (k < 447) ? w1[(size_t)k * 256 + j] : 0.0f;
            if (k < 384) v *= (1.0f / 3.0f);
            w1T[(size_t)j * 448 + k] = (_Float16)v;
        }
    } else if (j < 512) {
        const int jj = j - 256;
        w2T[(size_t)jj * 256 + t] = (_Float16)w2[(size_t)t * 256 + jj];
    } else {
        #pragma unroll
        for (int r = 0; r < 16; ++r)
            w3T[r * 256 + t] = (r < 3) ? (_Float16)w3[t * 3 + r] : (_Float16)0.0f;
    }
}

// ---- pgemm: P[v][j] = sum_k [feat|shape][v][k] * w1T[j][k] (1/3 folded) ----
// Swapped operands: A = w1T rows (hidden), B = vertex rows -> C cols = vertex,
// C rows = 4 consecutive hidden -> 8B vector stores into P.
__global__ __launch_bounds__(256, 3)
void pgemm(const float* __restrict__ feat, const float* __restrict__ shp,
           const _Float16* __restrict__ w1T, _Float16* __restrict__ P, int nV)
{
    __shared__ _Float16 as[64 * 384];   // 48 KB, vertex-major
    const int tid = threadIdx.x;
    const int n0 = blockIdx.x * 64;
    const int lane = tid & 63, wv = tid >> 6;
    const int nbase = wv << 6, l15 = lane & 15, kq = lane >> 4;

    // stage A: 64 vertex rows x 384 f16 (12 chunks/thread)
    #pragma unroll
    for (int i = 0; i < 12; ++i) {
        const int id = tid + i * 256;
        const int row = id / 48;
        const int g = id - row * 48;
        int v = n0 + row; if (v >= nV) v = nV - 1;
        const float* s = (g < 32) ? (feat + (size_t)v * 256 + g * 8)
                                  : (shp  + (size_t)v * 128 + (g - 32) * 8);
        const float4 a = ((const float4*)s)[0];
        const float4 b = ((const float4*)s)[1];
        hv8 h = { (_Float16)a.x, (_Float16)a.y, (_Float16)a.z, (_Float16)a.w,
                  (_Float16)b.x, (_Float16)b.y, (_Float16)b.z, (_Float16)b.w };
        *(hv8*)(&as[swzA(row, g * 8)]) = h;
    }
    f32x4 acc[4][4];   // [hf][pf]
    #pragma unroll
    for (int hf = 0; hf < 4; ++hf)
        #pragma unroll
        for (int pf = 0; pf < 4; ++pf) acc[hf][pf] = (f32x4){0.f, 0.f, 0.f, 0.f};
    __syncthreads();

    // K-loop: 12 tiles; per-tile fragment loads, compiler-scheduled
    #pragma unroll
    for (int t = 0; t < 12; ++t) {
        hv8 aw[4], bv[4];
        #pragma unroll
        for (int hf = 0; hf < 4; ++hf)
            aw[hf] = *(const hv8*)(w1T + (size_t)(nbase + hf * 16 + l15) * 448 + (t << 5) + (kq << 3));
        #pragma unroll
        for (int pf = 0; pf < 4; ++pf)
            bv[pf] = *(const hv8*)(as + swzA(pf * 16 + l15, (t << 5) | (kq << 3)));
        __builtin_amdgcn_s_setprio(1);
        #pragma unroll
        for (int hf = 0; hf < 4; ++hf)
            #pragma unroll
            for (int pf = 0; pf < 4; ++pf)
                acc[hf][pf] = __builtin_amdgcn_mfma_f32_16x16x32_f16(aw[hf], bv[pf], acc[hf][pf], 0, 0, 0);
        __builtin_amdgcn_s_setprio(0);
    }

    // epilogue: v = n0 + pf*16 + l15 (C col), j0 = nbase + hf*16 + kq*4 (C rows)
    #pragma unroll
    for (int pf = 0; pf < 4; ++pf) {
        const int v = n0 + pf * 16 + l15;
        if (v < nV) {
            #pragma unroll
            for (int hf = 0; hf < 4; ++hf) {
                const int j0 = nbase + hf * 16 + (kq << 2);
                hv4 hw;
                #pragma unroll
                for (int r = 0; r < 4; ++r) hw[r] = (_Float16)acc[hf][pf][r];
                *(hv4*)(P + (size_t)v * 256 + j0) = hw;
            }
        }
    }
}

// ---- main fused pixel kernel: 512 thr / 8 waves, swapped-operand MFMA ----
__global__ __launch_bounds__(512, 6)
void renderer(const int* __restrict__ pix, const float* __restrict__ bary,
              const int* __restrict__ faces,
              const _Float16* __restrict__ P,
              const float* __restrict__ color_bg,
              const float* __restrict__ b2g,
              const float* __restrict__ b3g,
              const _Float16* __restrict__ w1T,
              const _Float16* __restrict__ w2T,
              const _Float16* __restrict__ w3T,
              const float* __restrict__ b1p,
              float* __restrict__ out)
{
    __shared__ _Float16 embs[64 * 64];    // 8 KB
    __shared__ _Float16 pb[64 * 256];     // 32 KB: blend -> h1 (in-place) -> h2
    __shared__ int   vidx[TILE_M][3];
    __shared__ float bcs[TILE_M][3];

    const int tid = threadIdx.x;
    const int cpx = gridDim.x >> 3;
    const int bid = (blockIdx.x & 7) * cpx + (blockIdx.x >> 3);   // XCD-aware
    const int n0  = bid * TILE_M;

    const int lane  = tid & 63;
    const int wv    = tid >> 6;          // 0..7
    const int nbase = wv << 5;           // wave's 32 hidden cols
    const int l15   = lane & 15;
    const int kq    = lane >> 4;

    if (tid < TILE_M) {
        const int n = n0 + tid;
        const int face = pix[n];
        vidx[tid][0] = faces[face * 3 + 0];
        vidx[tid][1] = faces[face * 3 + 1];
        vidx[tid][2] = faces[face * 3 + 2];
        bcs[tid][0] = bary[n * 3 + 0];
        bcs[tid][1] = bary[n * 3 + 1];
        bcs[tid][2] = bary[n * 3 + 2];
    }
    __syncthreads();

    const int gp = tid >> 5;            // 0..15 : pixel within batch
    const int c8 = (tid & 31) << 3;     // col chunk (32 lanes cover a 512B row)

    // gather: 4 batches x 16 px; 2-deep ping-pong (T14)
    hv8 g0[3], g1[3];
    auto loadG = [&](hv8* g, const int b) {
        const int p = b * 16 + gp;
        g[0] = *(const hv8*)(P + (size_t)vidx[p][0] * 256 + c8);
        g[1] = *(const hv8*)(P + (size_t)vidx[p][1] * 256 + c8);
        g[2] = *(const hv8*)(P + (size_t)vidx[p][2] * 256 + c8);
    };
    auto blendG = [&](hv8* g, const int b) {
        const int p = b * 16 + gp;
        const _Float16 c0 = (_Float16)bcs[p][0];
        const _Float16 c1 = (_Float16)bcs[p][1];
        const _Float16 c2 = (_Float16)bcs[p][2];
        *(hv8*)(&pb[swzH(p, c8)]) = g[0] * c0 + g[1] * c1 + g[2] * c2;
    };

    loadG(g0, 0);
    loadG(g1, 1);

    // --- emb (NeRF embed of bary) -> embs; 8 vals/thread, one 16B store ---
    {
        const int p = tid >> 3;            // 0..63
        const int e8 = (tid & 7) << 3;     // slot base
        const float c0 = bcs[p][0], c1 = bcs[p][1], c2 = bcs[p][2];
        hv8 h;
        #pragma unroll
        for (int i = 0; i < 8; ++i) {
            const int s = e8 + i;
            float v;
            if (s < 3) v = (s == 0) ? c0 : ((s == 1) ? c1 : c2);
            else if (s < 63) {
                const int q = s - 3;
                const int f = q / 6;
                const int rem = q - f * 6;
                const int d = (rem >= 3) ? rem - 3 : rem;
                const float bd = (d == 0) ? c0 : ((d == 1) ? c1 : c2);
                const float arg = bd * (float)(1 << f);
                v = (rem < 3) ? __sinf(arg) : __cosf(arg);
            } else v = 0.0f;
            h[i] = (_Float16)v;
        }
        *(hv8*)(&embs[swzE(p, e8)]) = h;
    }

    // drain: blend b, re-issue b+2 into the freed slot
    blendG(g0, 0); loadG(g0, 2);
    blendG(g1, 1); loadG(g1, 3);
    blendG(g0, 2);
    blendG(g1, 3);

    // acc[hf][pf]: rows = 4 consecutive hidden (nbase+hf*16+kq*4+r), col = pixel
    f32x4 acc[2][4];
    #pragma unroll
    for (int hf = 0; hf < 2; ++hf) {
        const float4 bb = *(const float4*)(b1p + nbase + hf * 16 + (kq << 2));
        #pragma unroll
        for (int pf = 0; pf < 4; ++pf)
            acc[hf][pf] = (f32x4){bb.x, bb.y, bb.z, bb.w};
    }
    __syncthreads();   // embs + pb(blend) ready

    // --- layer-1 emb MFMA (2 K-tiles): A = w1T rows (weights), B = emb rows ---
    #pragma unroll
    for (int t = 0; t < 2; ++t) {
        hv8 aw[2], be[4];
        #pragma unroll
        for (int hf = 0; hf < 2; ++hf)
            aw[hf] = *(const hv8*)(w1T + (size_t)(nbase + hf * 16 + l15) * 448 + 384 + (t << 5) + (kq << 3));
        #pragma unroll
        for (int pf = 0; pf < 4; ++pf)
            be[pf] = *(const hv8*)(embs + swzE(pf * 16 + l15, (t << 5) | (kq << 3)));
        __builtin_amdgcn_s_setprio(1);
        #pragma unroll
        for (int hf = 0; hf < 2; ++hf)
            #pragma unroll
            for (int pf = 0; pf < 4; ++pf)
                acc[hf][pf] = __builtin_amdgcn_mfma_f32_16x16x32_f16(aw[hf], be[pf], acc[hf][pf], 0, 0, 0);
        __builtin_amdgcn_s_setprio(0);
    }

    // --- layer-1 epilogue: h1 = relu(acc + blend) via b64 RMW; acc = b2 (float4) ---
    #pragma unroll
    for (int hf = 0; hf < 2; ++hf) {
        const int h0 = nbase + hf * 16 + (kq << 2);
        const float4 b2v = *(const float4*)(b2g + h0);
        #pragma unroll
        for (int pf = 0; pf < 4; ++pf) {
            const int sl = swzH(pf * 16 + l15, h0);
            hv4 pv = *(hv4*)(&pb[sl]);
            hv4 hw;
            #pragma unroll
            for (int r = 0; r < 4; ++r)
                hw[r] = (_Float16)fmaxf(acc[hf][pf][r] + (float)pv[r], 0.0f);
            *(hv4*)(&pb[sl]) = hw;
            acc[hf][pf] = (f32x4){b2v.x, b2v.y, b2v.z, b2v.w};
        }
    }
    __syncthreads();   // h1 ready

    // --- layer-2: 8 K-tiles; A = w2T rows, B = h1 rows (both b128) ---
    #pragma unroll
    for (int t = 0; t < 8; ++t) {
        hv8 aw[2], bh[4];
        #pragma unroll
        for (int hf = 0; hf < 2; ++hf)
            aw[hf] = *(const hv8*)(w2T + (size_t)(nbase + hf * 16 + l15) * 256 + (t << 5) + (kq << 3));
        #pragma unroll
        for (int pf = 0; pf < 4; ++pf)
            bh[pf] = *(const hv8*)(pb + swzH(pf * 16 + l15, (t << 5) | (kq << 3)));
        __builtin_amdgcn_s_setprio(1);
        #pragma unroll
        for (int hf = 0; hf < 2; ++hf)
            #pragma unroll
            for (int pf = 0; pf < 4; ++pf)
                acc[hf][pf] = __builtin_amdgcn_mfma_f32_16x16x32_f16(aw[hf], bh[pf], acc[hf][pf], 0, 0, 0);
        __builtin_amdgcn_s_setprio(0);
    }

    __syncthreads();   // all layer-2 B-reads done
    // --- h2 = relu(acc) -> pb via b64 stores ---
    #pragma unroll
    for (int hf = 0; hf < 2; ++hf) {
        const int h0 = nbase + hf * 16 + (kq << 2);
        #pragma unroll
        for (int pf = 0; pf < 4; ++pf) {
            hv4 hw;
            #pragma unroll
            for (int r = 0; r < 4; ++r)
                hw[r] = (_Float16)fmaxf(acc[hf][pf][r], 0.0f);
            *(hv4*)(&pb[swzH(pf * 16 + l15, h0)]) = hw;
        }
    }

    // --- layer-3 A fragments (waves 0-3); latency hides under barrier wait ---
    hv8 aw3[8];
    if (wv < 4) {
        #pragma unroll
        for (int t = 0; t < 8; ++t)
            aw3[t] = *(const hv8*)(w3T + l15 * 256 + (t << 5) + (kq << 3));
    }
    __syncthreads();

    // --- layer-3: wave wv (0..3) owns pixels [wv*16, wv*16+16); float4 out ---
    if (wv < 4) {
        f32x4 acc3 = (f32x4){0.f, 0.f, 0.f, 0.f};
        #pragma unroll
        for (int t = 0; t < 8; ++t) {
            const hv8 bh = *(const hv8*)(pb + swzH((wv << 4) + l15, (t << 5) | (kq << 3)));
            acc3 = __builtin_amdgcn_mfma_f32_16x16x32_f16(aw3[t], bh, acc3, 0, 0, 0);
        }
        if (kq == 0) {   // rows 0..3 = channels
            const int n = n0 + (wv << 4) + l15;
            const bool m = pix[n] > 0;
            const int b = n >> 16;               // H*W = 65536
            float4 o4;
            o4.x = m ? (fmaxf(acc3[0] + b3g[0], 0.f) - 1.0f) : color_bg[b * 3 + 0];
            o4.y = m ? (fmaxf(acc3[1] + b3g[1], 0.f) - 1.0f) : color_bg[b * 3 + 1];
            o4.z = m ? (fmaxf(acc3[2] + b3g[2], 0.f) - 1.0f) : color_bg[b * 3 + 2];
            o4.w = m ? 1.0f : 0.0f;
            *(float4*)(out + (size_t)n * 4) = o4;
        }
    }
}

extern "C" void kernel_launch(void* const* d_in, const int* in_sizes, int n_in,
                              void* d_out, int out_size, void* d_ws, size_t ws_size,
                              hipStream_t stream) {
    const int*   pix      = (const int*)  d_in[0];
    const float* bary     = (const float*)d_in[1];
    const int*   faces    = (const int*)  d_in[2];
    const float* feature  = (const float*)d_in[3];
    const float* shapef   = (const float*)d_in[4];
    const float* color_bg = (const float*)d_in[5];
    const float* style    = (const float*)d_in[6];
    const float* w1       = (const float*)d_in[7];
    const float* b1       = (const float*)d_in[8];
    const float* w2       = (const float*)d_in[9];
    const float* b2       = (const float*)d_in[10];
    const float* w3       = (const float*)d_in[11];
    const float* b3       = (const float*)d_in[12];
    float* out = (float*)d_out;

    const int nV = in_sizes[3] / 256;                         // 50000 vertices

    char* ws = (char*)d_ws;
    _Float16* w1T  = (_Float16*)ws;                           // 229,376 B
    _Float16* w2T  = (_Float16*)(ws + 229376);                // 131,072 B
    float*    b1p  = (float*)   (ws + 360448);                // 1,024 B
    _Float16* w3T  = (_Float16*)(ws + 361472);                // 8,192 B
    _Float16* Ptab = (_Float16*)(ws + 369664);                // nV*256*2 = 25.6 MB

    hipLaunchKernelGGL(prep_weights, dim3(513), dim3(256), 0, stream,
                       style, w1, b1, w2, w3, w1T, w2T, w3T, b1p);
    hipLaunchKernelGGL(pgemm, dim3((nV + 63) / 64), dim3(256), 0, stream,
                       feature, shapef, w1T, Ptab, nV);

    const int npix = in_sizes[0];                             // 262144
    hipLaunchKernelGGL(renderer, dim3(npix / TILE_M), dim3(512), 0, stream,
                       pix, bary, faces, Ptab, color_bg,
                       b2, b3, w1T, w2T, w3T, b1p, out);
}

// Round 21
// 162.747 us; speedup vs baseline: 1.0396x; 1.0396x over previous
//
#include <hip/hip_runtime.h>
#include <math.h>

// DifferentiableMultiMLPRenderer — round 21: r20 + padded LDS strides.
// r18's b64 epilogue accesses 4-way-conflict under the 16B-granule XOR swizzle
// (conflicts 2.6M->7.9M). All renderer LDS accesses are now vectorized, so
// padding works: pb stride 264 (528B row: b128 tiles all 32 banks, b64 2-way
// free), embs stride 72. Also deletes the XOR from every LDS address (~VALU cut).
// LDS 44.5KB -> still 3 blocks/CU at (512,6). pgemm/prep unchanged from r20.

typedef _Float16 hv8 __attribute__((ext_vector_type(8)));
typedef _Float16 hv4 __attribute__((ext_vector_type(4)));
typedef __attribute__((ext_vector_type(4))) float f32x4;

#define TILE_M 64
#define PB_STR 264
#define EB_STR 72

__device__ inline int swzA(int row, int k) { return row * 384 + (k ^ ((row & 7) << 3)); }

// ---- prep: fold style into b1; build f16 weights: w1T (1/3 folded), w2T, w3T ----
__global__ __launch_bounds__(256)
void prep_weights(const float* __restrict__ style,
                  const float* __restrict__ w1, const float* __restrict__ b1,
                  const float* __restrict__ w2, const float* __restrict__ w3,
                  _Float16* __restrict__ w1T, _Float16* __restrict__ w2T,
                  _Float16* __restrict__ w3T, float* __restrict__ b1p)
{
    const int j = blockIdx.x;
    const int t = threadIdx.x;
    if (j < 256) {
        float part = style[t] * w1[(size_t)(447 + t) * 256 + j];
        #pragma unroll
        for (int off = 32; off; off >>= 1) part += __shfl_down(part, off, 64);
        __shared__ float red[4];
        if ((t & 63) == 0) red[t >> 6] = part;
        __syncthreads();
        if (t == 0) b1p[j] = b1[j] + red[0] + red[1] + red[2] + red[3];
        for (int k = t; k < 448; k += 256) {
            float v = (k < 447) ? w1[(size_t)k * 256 + j] : 0.0f;
            if (k < 384) v *= (1.0f / 3.0f);
            w1T[(size_t)j * 448 + k] = (_Float16)v;
        }
    } else if (j < 512) {
        const int jj = j - 256;
        w2T[(size_t)jj * 256 + t] = (_Float16)w2[(size_t)t * 256 + jj];
    } else {
        #pragma unroll
        for (int r = 0; r < 16; ++r)
            w3T[r * 256 + t] = (r < 3) ? (_Float16)w3[t * 3 + r] : (_Float16)0.0f;
    }
}

// ---- pgemm: P[v][j] = sum_k [feat|shape][v][k] * w1T[j][k] (1/3 folded) ----
__global__ __launch_bounds__(256, 3)
void pgemm(const float* __restrict__ feat, const float* __restrict__ shp,
           const _Float16* __restrict__ w1T, _Float16* __restrict__ P, int nV)
{
    __shared__ _Float16 as[64 * 384];   // 48 KB, vertex-major
    const int tid = threadIdx.x;
    const int n0 = blockIdx.x * 64;
    const int lane = tid & 63, wv = tid >> 6;
    const int nbase = wv << 6, l15 = lane & 15, kq = lane >> 4;

    #pragma unroll
    for (int i = 0; i < 12; ++i) {
        const int id = tid + i * 256;
        const int row = id / 48;
        const int g = id - row * 48;
        int v = n0 + row; if (v >= nV) v = nV - 1;
        const float* s = (g < 32) ? (feat + (size_t)v * 256 + g * 8)
                                  : (shp  + (size_t)v * 128 + (g - 32) * 8);
        const float4 a = ((const float4*)s)[0];
        const float4 b = ((const float4*)s)[1];
        hv8 h = { (_Float16)a.x, (_Float16)a.y, (_Float16)a.z, (_Float16)a.w,
                  (_Float16)b.x, (_Float16)b.y, (_Float16)b.z, (_Float16)b.w };
        *(hv8*)(&as[swzA(row, g * 8)]) = h;
    }
    f32x4 acc[4][4];   // [hf][pf]
    #pragma unroll
    for (int hf = 0; hf < 4; ++hf)
        #pragma unroll
        for (int pf = 0; pf < 4; ++pf) acc[hf][pf] = (f32x4){0.f, 0.f, 0.f, 0.f};
    __syncthreads();

    #pragma unroll
    for (int t = 0; t < 12; ++t) {
        hv8 aw[4], bv[4];
        #pragma unroll
        for (int hf = 0; hf < 4; ++hf)
            aw[hf] = *(const hv8*)(w1T + (size_t)(nbase + hf * 16 + l15) * 448 + (t << 5) + (kq << 3));
        #pragma unroll
        for (int pf = 0; pf < 4; ++pf)
            bv[pf] = *(const hv8*)(as + swzA(pf * 16 + l15, (t << 5) | (kq << 3)));
        __builtin_amdgcn_s_setprio(1);
        #pragma unroll
        for (int hf = 0; hf < 4; ++hf)
            #pragma unroll
            for (int pf = 0; pf < 4; ++pf)
                acc[hf][pf] = __builtin_amdgcn_mfma_f32_16x16x32_f16(aw[hf], bv[pf], acc[hf][pf], 0, 0, 0);
        __builtin_amdgcn_s_setprio(0);
    }

    #pragma unroll
    for (int pf = 0; pf < 4; ++pf) {
        const int v = n0 + pf * 16 + l15;
        if (v < nV) {
            #pragma unroll
            for (int hf = 0; hf < 4; ++hf) {
                const int j0 = nbase + hf * 16 + (kq << 2);
                hv4 hw;
                #pragma unroll
                for (int r = 0; r < 4; ++r) hw[r] = (_Float16)acc[hf][pf][r];
                *(hv4*)(P + (size_t)v * 256 + j0) = hw;
            }
        }
    }
}

// ---- main fused pixel kernel: 512 thr / 8 waves, swapped-operand MFMA ----
__global__ __launch_bounds__(512, 6)
void renderer(const int* __restrict__ pix, const float* __restrict__ bary,
              const int* __restrict__ faces,
              const _Float16* __restrict__ P,
              const float* __restrict__ color_bg,
              const float* __restrict__ b2g,
              const float* __restrict__ b3g,
              const _Float16* __restrict__ w1T,
              const _Float16* __restrict__ w2T,
              const _Float16* __restrict__ w3T,
              const float* __restrict__ b1p,
              float* __restrict__ out)
{
    __shared__ _Float16 embs[64 * EB_STR];   // 9.2 KB
    __shared__ _Float16 pb[64 * PB_STR];     // 33.8 KB: blend -> h1 -> h2
    __shared__ int   vidx[TILE_M][3];
    __shared__ float bcs[TILE_M][3];

    const int tid = threadIdx.x;
    const int cpx = gridDim.x >> 3;
    const int bid = (blockIdx.x & 7) * cpx + (blockIdx.x >> 3);   // XCD-aware
    const int n0  = bid * TILE_M;

    const int lane  = tid & 63;
    const int wv    = tid >> 6;          // 0..7
    const int nbase = wv << 5;           // wave's 32 hidden cols
    const int l15   = lane & 15;
    const int kq    = lane >> 4;

    if (tid < TILE_M) {
        const int n = n0 + tid;
        const int face = pix[n];
        vidx[tid][0] = faces[face * 3 + 0];
        vidx[tid][1] = faces[face * 3 + 1];
        vidx[tid][2] = faces[face * 3 + 2];
        bcs[tid][0] = bary[n * 3 + 0];
        bcs[tid][1] = bary[n * 3 + 1];
        bcs[tid][2] = bary[n * 3 + 2];
    }
    __syncthreads();

    const int gp = tid >> 5;            // 0..15 : pixel within batch
    const int c8 = (tid & 31) << 3;     // col chunk (32 lanes cover a 512B row)

    // gather: 4 batches x 16 px; 2-deep ping-pong (T14)
    hv8 g0[3], g1[3];
    auto loadG = [&](hv8* g, const int b) {
        const int p = b * 16 + gp;
        g[0] = *(const hv8*)(P + (size_t)vidx[p][0] * 256 + c8);
        g[1] = *(const hv8*)(P + (size_t)vidx[p][1] * 256 + c8);
        g[2] = *(const hv8*)(P + (size_t)vidx[p][2] * 256 + c8);
    };
    auto blendG = [&](hv8* g, const int b) {
        const int p = b * 16 + gp;
        const _Float16 c0 = (_Float16)bcs[p][0];
        const _Float16 c1 = (_Float16)bcs[p][1];
        const _Float16 c2 = (_Float16)bcs[p][2];
        *(hv8*)(&pb[p * PB_STR + c8]) = g[0] * c0 + g[1] * c1 + g[2] * c2;
    };

    loadG(g0, 0);
    loadG(g1, 1);

    // --- emb (NeRF embed of bary) -> embs; 8 vals/thread, one 16B store ---
    {
        const int p = tid >> 3;            // 0..63
        const int e8 = (tid & 7) << 3;     // slot base
        const float c0 = bcs[p][0], c1 = bcs[p][1], c2 = bcs[p][2];
        hv8 h;
        #pragma unroll
        for (int i = 0; i < 8; ++i) {
            const int s = e8 + i;
            float v;
            if (s < 3) v = (s == 0) ? c0 : ((s == 1) ? c1 : c2);
            else if (s < 63) {
                const int q = s - 3;
                const int f = q / 6;
                const int rem = q - f * 6;
                const int d = (rem >= 3) ? rem - 3 : rem;
                const float bd = (d == 0) ? c0 : ((d == 1) ? c1 : c2);
                const float arg = bd * (float)(1 << f);
                v = (rem < 3) ? __sinf(arg) : __cosf(arg);
            } else v = 0.0f;
            h[i] = (_Float16)v;
        }
        *(hv8*)(&embs[p * EB_STR + e8]) = h;
    }

    // drain: blend b, re-issue b+2 into the freed slot
    blendG(g0, 0); loadG(g0, 2);
    blendG(g1, 1); loadG(g1, 3);
    blendG(g0, 2);
    blendG(g1, 3);

    // acc[hf][pf]: rows = 4 consecutive hidden (nbase+hf*16+kq*4+r), col = pixel
    f32x4 acc[2][4];
    #pragma unroll
    for (int hf = 0; hf < 2; ++hf) {
        const float4 bb = *(const float4*)(b1p + nbase + hf * 16 + (kq << 2));
        #pragma unroll
        for (int pf = 0; pf < 4; ++pf)
            acc[hf][pf] = (f32x4){bb.x, bb.y, bb.z, bb.w};
    }
    __syncthreads();   // embs + pb(blend) ready

    // --- layer-1 emb MFMA (2 K-tiles): A = w1T rows (weights), B = emb rows ---
    #pragma unroll
    for (int t = 0; t < 2; ++t) {
        hv8 aw[2], be[4];
        #pragma unroll
        for (int hf = 0; hf < 2; ++hf)
            aw[hf] = *(const hv8*)(w1T + (size_t)(nbase + hf * 16 + l15) * 448 + 384 + (t << 5) + (kq << 3));
        #pragma unroll
        for (int pf = 0; pf < 4; ++pf)
            be[pf] = *(const hv8*)(embs + (pf * 16 + l15) * EB_STR + ((t << 5) | (kq << 3)));
        __builtin_amdgcn_s_setprio(1);
        #pragma unroll
        for (int hf = 0; hf < 2; ++hf)
            #pragma unroll
            for (int pf = 0; pf < 4; ++pf)
                acc[hf][pf] = __builtin_amdgcn_mfma_f32_16x16x32_f16(aw[hf], be[pf], acc[hf][pf], 0, 0, 0);
        __builtin_amdgcn_s_setprio(0);
    }

    // --- layer-1 epilogue: h1 = relu(acc + blend) via b64 RMW; acc = b2 (float4) ---
    #pragma unroll
    for (int hf = 0; hf < 2; ++hf) {
        const int h0 = nbase + hf * 16 + (kq << 2);
        const float4 b2v = *(const float4*)(b2g + h0);
        #pragma unroll
        for (int pf = 0; pf < 4; ++pf) {
            const int sl = (pf * 16 + l15) * PB_STR + h0;
            hv4 pv = *(hv4*)(&pb[sl]);
            hv4 hw;
            #pragma unroll
            for (int r = 0; r < 4; ++r)
                hw[r] = (_Float16)fmaxf(acc[hf][pf][r] + (float)pv[r], 0.0f);
            *(hv4*)(&pb[sl]) = hw;
            acc[hf][pf] = (f32x4){b2v.x, b2v.y, b2v.z, b2v.w};
        }
    }
    __syncthreads();   // h1 ready

    // --- layer-2: 8 K-tiles; A = w2T rows, B = h1 rows (both b128) ---
    #pragma unroll
    for (int t = 0; t < 8; ++t) {
        hv8 aw[2], bh[4];
        #pragma unroll
        for (int hf = 0; hf < 2; ++hf)
            aw[hf] = *(const hv8*)(w2T + (size_t)(nbase + hf * 16 + l15) * 256 + (t << 5) + (kq << 3));
        #pragma unroll
        for (int pf = 0; pf < 4; ++pf)
            bh[pf] = *(const hv8*)(pb + (pf * 16 + l15) * PB_STR + ((t << 5) | (kq << 3)));
        __builtin_amdgcn_s_setprio(1);
        #pragma unroll
        for (int hf = 0; hf < 2; ++hf)
            #pragma unroll
            for (int pf = 0; pf < 4; ++pf)
                acc[hf][pf] = __builtin_amdgcn_mfma_f32_16x16x32_f16(aw[hf], bh[pf], acc[hf][pf], 0, 0, 0);
        __builtin_amdgcn_s_setprio(0);
    }

    __syncthreads();   // all layer-2 B-reads done
    // --- h2 = relu(acc) -> pb via b64 stores ---
    #pragma unroll
    for (int hf = 0; hf < 2; ++hf) {
        const int h0 = nbase + hf * 16 + (kq << 2);
        #pragma unroll
        for (int pf = 0; pf < 4; ++pf) {
            hv4 hw;
            #pragma unroll
            for (int r = 0; r < 4; ++r)
                hw[r] = (_Float16)fmaxf(acc[hf][pf][r], 0.0f);
            *(hv4*)(&pb[(pf * 16 + l15) * PB_STR + h0]) = hw;
        }
    }

    // --- layer-3 A fragments (waves 0-3); latency hides under barrier wait ---
    hv8 aw3[8];
    if (wv < 4) {
        #pragma unroll
        for (int t = 0; t < 8; ++t)
            aw3[t] = *(const hv8*)(w3T + l15 * 256 + (t << 5) + (kq << 3));
    }
    __syncthreads();

    // --- layer-3: wave wv (0..3) owns pixels [wv*16, wv*16+16); float4 out ---
    if (wv < 4) {
        f32x4 acc3 = (f32x4){0.f, 0.f, 0.f, 0.f};
        #pragma unroll
        for (int t = 0; t < 8; ++t) {
            const hv8 bh = *(const hv8*)(pb + ((wv << 4) + l15) * PB_STR + ((t << 5) | (kq << 3)));
            acc3 = __builtin_amdgcn_mfma_f32_16x16x32_f16(aw3[t], bh, acc3, 0, 0, 0);
        }
        if (kq == 0) {   // rows 0..3 = channels
            const int n = n0 + (wv << 4) + l15;
            const bool m = pix[n] > 0;
            const int b = n >> 16;               // H*W = 65536
            float4 o4;
            o4.x = m ? (fmaxf(acc3[0] + b3g[0], 0.f) - 1.0f) : color_bg[b * 3 + 0];
            o4.y = m ? (fmaxf(acc3[1] + b3g[1], 0.f) - 1.0f) : color_bg[b * 3 + 1];
            o4.z = m ? (fmaxf(acc3[2] + b3g[2], 0.f) - 1.0f) : color_bg[b * 3 + 2];
            o4.w = m ? 1.0f : 0.0f;
            *(float4*)(out + (size_t)n * 4) = o4;
        }
    }
}

extern "C" void kernel_launch(void* const* d_in, const int* in_sizes, int n_in,
                              void* d_out, int out_size, void* d_ws, size_t ws_size,
                              hipStream_t stream) {
    const int*   pix      = (const int*)  d_in[0];
    const float* bary     = (const float*)d_in[1];
    const int*   faces    = (const int*)  d_in[2];
    const float* feature  = (const float*)d_in[3];
    const float* shapef   = (const float*)d_in[4];
    const float* color_bg = (const float*)d_in[5];
    const float* style    = (const float*)d_in[6];
    const float* w1       = (const float*)d_in[7];
    const float* b1       = (const float*)d_in[8];
    const float* w2       = (const float*)d_in[9];
    const float* b2       = (const float*)d_in[10];
    const float* w3       = (const float*)d_in[11];
    const float* b3       = (const float*)d_in[12];
    float* out = (float*)d_out;

    const int nV = in_sizes[3] / 256;                         // 50000 vertices

    char* ws = (char*)d_ws;
    _Float16* w1T  = (_Float16*)ws;                           // 229,376 B
    _Float16* w2T  = (_Float16*)(ws + 229376);                // 131,072 B
    float*    b1p  = (float*)   (ws + 360448);                // 1,024 B
    _Float16* w3T  = (_Float16*)(ws + 361472);                // 8,192 B
    _Float16* Ptab = (_Float16*)(ws + 369664);                // nV*256*2 = 25.6 MB

    hipLaunchKernelGGL(prep_weights, dim3(513), dim3(256), 0, stream,
                       style, w1, b1, w2, w3, w1T, w2T, w3T, b1p);
    hipLaunchKernelGGL(pgemm, dim3((nV + 63) / 64), dim3(256), 0, stream,
                       feature, shapef, w1T, Ptab, nV);

    const int npix = in_sizes[0];                             // 262144
    hipLaunchKernelGGL(renderer, dim3(npix / TILE_M), dim3(512), 0, stream,
                       pix, bary, faces, Ptab, color_bg,
                       b2, b3, w1T, w2T, w3T, b1p, out);
}

// Round 22
// 161.295 us; speedup vs baseline: 1.0490x; 1.0090x over previous
//
#include <hip/hip_runtime.h>
#include <math.h>

// DifferentiableMultiMLPRenderer — round 22: conflict-optimal LDS strides.
// r21's PB_STR=264 (132 dwords ≡ 4 mod 32) gives only 8 distinct bank-starts
// over the 16 rows of a b128 fragment read -> conflicts ROSE to 8.9M. Fix:
// PB_STR=268 (134 ≡ 6 mod 32: 6i mod 32 hits 16 distinct starts) and
// EB_STR=76 (38 ≡ 6). Everything else identical to r21.

typedef _Float16 hv8 __attribute__((ext_vector_type(8)));
typedef _Float16 hv4 __attribute__((ext_vector_type(4)));
typedef __attribute__((ext_vector_type(4))) float f32x4;

#define TILE_M 64
#define PB_STR 268
#define EB_STR 76

__device__ inline int swzA(int row, int k) { return row * 384 + (k ^ ((row & 7) << 3)); }

// ---- prep: fold style into b1; build f16 weights: w1T (1/3 folded), w2T, w3T ----
__global__ __launch_bounds__(256)
void prep_weights(const float* __restrict__ style,
                  const float* __restrict__ w1, const float* __restrict__ b1,
                  const float* __restrict__ w2, const float* __restrict__ w3,
                  _Float16* __restrict__ w1T, _Float16* __restrict__ w2T,
                  _Float16* __restrict__ w3T, float* __restrict__ b1p)
{
    const int j = blockIdx.x;
    const int t = threadIdx.x;
    if (j < 256) {
        float part = style[t] * w1[(size_t)(447 + t) * 256 + j];
        #pragma unroll
        for (int off = 32; off; off >>= 1) part += __shfl_down(part, off, 64);
        __shared__ float red[4];
        if ((t & 63) == 0) red[t >> 6] = part;
        __syncthreads();
        if (t == 0) b1p[j] = b1[j] + red[0] + red[1] + red[2] + red[3];
        for (int k = t; k < 448; k += 256) {
            float v = (k < 447) ? w1[(size_t)k * 256 + j] : 0.0f;
            if (k < 384) v *= (1.0f / 3.0f);
            w1T[(size_t)j * 448 + k] = (_Float16)v;
        }
    } else if (j < 512) {
        const int jj = j - 256;
        w2T[(size_t)jj * 256 + t] = (_Float16)w2[(size_t)t * 256 + jj];
    } else {
        #pragma unroll
        for (int r = 0; r < 16; ++r)
            w3T[r * 256 + t] = (r < 3) ? (_Float16)w3[t * 3 + r] : (_Float16)0.0f;
    }
}

// ---- pgemm: P[v][j] = sum_k [feat|shape][v][k] * w1T[j][k] (1/3 folded) ----
__global__ __launch_bounds__(256, 3)
void pgemm(const float* __restrict__ feat, const float* __restrict__ shp,
           const _Float16* __restrict__ w1T, _Float16* __restrict__ P, int nV)
{
    __shared__ _Float16 as[64 * 384];   // 48 KB, vertex-major
    const int tid = threadIdx.x;
    const int n0 = blockIdx.x * 64;
    const int lane = tid & 63, wv = tid >> 6;
    const int nbase = wv << 6, l15 = lane & 15, kq = lane >> 4;

    #pragma unroll
    for (int i = 0; i < 12; ++i) {
        const int id = tid + i * 256;
        const int row = id / 48;
        const int g = id - row * 48;
        int v = n0 + row; if (v >= nV) v = nV - 1;
        const float* s = (g < 32) ? (feat + (size_t)v * 256 + g * 8)
                                  : (shp  + (size_t)v * 128 + (g - 32) * 8);
        const float4 a = ((const float4*)s)[0];
        const float4 b = ((const float4*)s)[1];
        hv8 h = { (_Float16)a.x, (_Float16)a.y, (_Float16)a.z, (_Float16)a.w,
                  (_Float16)b.x, (_Float16)b.y, (_Float16)b.z, (_Float16)b.w };
        *(hv8*)(&as[swzA(row, g * 8)]) = h;
    }
    f32x4 acc[4][4];   // [hf][pf]
    #pragma unroll
    for (int hf = 0; hf < 4; ++hf)
        #pragma unroll
        for (int pf = 0; pf < 4; ++pf) acc[hf][pf] = (f32x4){0.f, 0.f, 0.f, 0.f};
    __syncthreads();

    #pragma unroll
    for (int t = 0; t < 12; ++t) {
        hv8 aw[4], bv[4];
        #pragma unroll
        for (int hf = 0; hf < 4; ++hf)
            aw[hf] = *(const hv8*)(w1T + (size_t)(nbase + hf * 16 + l15) * 448 + (t << 5) + (kq << 3));
        #pragma unroll
        for (int pf = 0; pf < 4; ++pf)
            bv[pf] = *(const hv8*)(as + swzA(pf * 16 + l15, (t << 5) | (kq << 3)));
        __builtin_amdgcn_s_setprio(1);
        #pragma unroll
        for (int hf = 0; hf < 4; ++hf)
            #pragma unroll
            for (int pf = 0; pf < 4; ++pf)
                acc[hf][pf] = __builtin_amdgcn_mfma_f32_16x16x32_f16(aw[hf], bv[pf], acc[hf][pf], 0, 0, 0);
        __builtin_amdgcn_s_setprio(0);
    }

    #pragma unroll
    for (int pf = 0; pf < 4; ++pf) {
        const int v = n0 + pf * 16 + l15;
        if (v < nV) {
            #pragma unroll
            for (int hf = 0; hf < 4; ++hf) {
                const int j0 = nbase + hf * 16 + (kq << 2);
                hv4 hw;
                #pragma unroll
                for (int r = 0; r < 4; ++r) hw[r] = (_Float16)acc[hf][pf][r];
                *(hv4*)(P + (size_t)v * 256 + j0) = hw;
            }
        }
    }
}

// ---- main fused pixel kernel: 512 thr / 8 waves, swapped-operand MFMA ----
__global__ __launch_bounds__(512, 6)
void renderer(const int* __restrict__ pix, const float* __restrict__ bary,
              const int* __restrict__ faces,
              const _Float16* __restrict__ P,
              const float* __restrict__ color_bg,
              const float* __restrict__ b2g,
              const float* __restrict__ b3g,
              const _Float16* __restrict__ w1T,
              const _Float16* __restrict__ w2T,
              const _Float16* __restrict__ w3T,
              const float* __restrict__ b1p,
              float* __restrict__ out)
{
    __shared__ _Float16 embs[64 * EB_STR];   // 9.7 KB
    __shared__ _Float16 pb[64 * PB_STR];     // 34.3 KB: blend -> h1 -> h2
    __shared__ int   vidx[TILE_M][3];
    __shared__ float bcs[TILE_M][3];

    const int tid = threadIdx.x;
    const int cpx = gridDim.x >> 3;
    const int bid = (blockIdx.x & 7) * cpx + (blockIdx.x >> 3);   // XCD-aware
    const int n0  = bid * TILE_M;

    const int lane  = tid & 63;
    const int wv    = tid >> 6;          // 0..7
    const int nbase = wv << 5;           // wave's 32 hidden cols
    const int l15   = lane & 15;
    const int kq    = lane >> 4;

    if (tid < TILE_M) {
        const int n = n0 + tid;
        const int face = pix[n];
        vidx[tid][0] = faces[face * 3 + 0];
        vidx[tid][1] = faces[face * 3 + 1];
        vidx[tid][2] = faces[face * 3 + 2];
        bcs[tid][0] = bary[n * 3 + 0];
        bcs[tid][1] = bary[n * 3 + 1];
        bcs[tid][2] = bary[n * 3 + 2];
    }
    __syncthreads();

    const int gp = tid >> 5;            // 0..15 : pixel within batch
    const int c8 = (tid & 31) << 3;     // col chunk (32 lanes cover a 512B row)

    // gather: 4 batches x 16 px; 2-deep ping-pong (T14)
    hv8 g0[3], g1[3];
    auto loadG = [&](hv8* g, const int b) {
        const int p = b * 16 + gp;
        g[0] = *(const hv8*)(P + (size_t)vidx[p][0] * 256 + c8);
        g[1] = *(const hv8*)(P + (size_t)vidx[p][1] * 256 + c8);
        g[2] = *(const hv8*)(P + (size_t)vidx[p][2] * 256 + c8);
    };
    auto blendG = [&](hv8* g, const int b) {
        const int p = b * 16 + gp;
        const _Float16 c0 = (_Float16)bcs[p][0];
        const _Float16 c1 = (_Float16)bcs[p][1];
        const _Float16 c2 = (_Float16)bcs[p][2];
        *(hv8*)(&pb[p * PB_STR + c8]) = g[0] * c0 + g[1] * c1 + g[2] * c2;
    };

    loadG(g0, 0);
    loadG(g1, 1);

    // --- emb (NeRF embed of bary) -> embs; 8 vals/thread, one 16B store ---
    {
        const int p = tid >> 3;            // 0..63
        const int e8 = (tid & 7) << 3;     // slot base
        const float c0 = bcs[p][0], c1 = bcs[p][1], c2 = bcs[p][2];
        hv8 h;
        #pragma unroll
        for (int i = 0; i < 8; ++i) {
            const int s = e8 + i;
            float v;
            if (s < 3) v = (s == 0) ? c0 : ((s == 1) ? c1 : c2);
            else if (s < 63) {
                const int q = s - 3;
                const int f = q / 6;
                const int rem = q - f * 6;
                const int d = (rem >= 3) ? rem - 3 : rem;
                const float bd = (d == 0) ? c0 : ((d == 1) ? c1 : c2);
                const float arg = bd * (float)(1 << f);
                v = (rem < 3) ? __sinf(arg) : __cosf(arg);
            } else v = 0.0f;
            h[i] = (_Float16)v;
        }
        *(hv8*)(&embs[p * EB_STR + e8]) = h;
    }

    // drain: blend b, re-issue b+2 into the freed slot
    blendG(g0, 0); loadG(g0, 2);
    blendG(g1, 1); loadG(g1, 3);
    blendG(g0, 2);
    blendG(g1, 3);

    // acc[hf][pf]: rows = 4 consecutive hidden (nbase+hf*16+kq*4+r), col = pixel
    f32x4 acc[2][4];
    #pragma unroll
    for (int hf = 0; hf < 2; ++hf) {
        const float4 bb = *(const float4*)(b1p + nbase + hf * 16 + (kq << 2));
        #pragma unroll
        for (int pf = 0; pf < 4; ++pf)
            acc[hf][pf] = (f32x4){bb.x, bb.y, bb.z, bb.w};
    }
    __syncthreads();   // embs + pb(blend) ready

    // --- layer-1 emb MFMA (2 K-tiles): A = w1T rows (weights), B = emb rows ---
    #pragma unroll
    for (int t = 0; t < 2; ++t) {
        hv8 aw[2], be[4];
        #pragma unroll
        for (int hf = 0; hf < 2; ++hf)
            aw[hf] = *(const hv8*)(w1T + (size_t)(nbase + hf * 16 + l15) * 448 + 384 + (t << 5) + (kq << 3));
        #pragma unroll
        for (int pf = 0; pf < 4; ++pf)
            be[pf] = *(const hv8*)(embs + (pf * 16 + l15) * EB_STR + ((t << 5) | (kq << 3)));
        __builtin_amdgcn_s_setprio(1);
        #pragma unroll
        for (int hf = 0; hf < 2; ++hf)
            #pragma unroll
            for (int pf = 0; pf < 4; ++pf)
                acc[hf][pf] = __builtin_amdgcn_mfma_f32_16x16x32_f16(aw[hf], be[pf], acc[hf][pf], 0, 0, 0);
        __builtin_amdgcn_s_setprio(0);
    }

    // --- layer-1 epilogue: h1 = relu(acc + blend) via b64 RMW; acc = b2 (float4) ---
    #pragma unroll
    for (int hf = 0; hf < 2; ++hf) {
        const int h0 = nbase + hf * 16 + (kq << 2);
        const float4 b2v = *(const float4*)(b2g + h0);
        #pragma unroll
        for (int pf = 0; pf < 4; ++pf) {
            const int sl = (pf * 16 + l15) * PB_STR + h0;
            hv4 pv = *(hv4*)(&pb[sl]);
            hv4 hw;
            #pragma unroll
            for (int r = 0; r < 4; ++r)
                hw[r] = (_Float16)fmaxf(acc[hf][pf][r] + (float)pv[r], 0.0f);
            *(hv4*)(&pb[sl]) = hw;
            acc[hf][pf] = (f32x4){b2v.x, b2v.y, b2v.z, b2v.w};
        }
    }
    __syncthreads();   // h1 ready

    // --- layer-2: 8 K-tiles; A = w2T rows, B = h1 rows (both b128) ---
    #pragma unroll
    for (int t = 0; t < 8; ++t) {
        hv8 aw[2], bh[4];
        #pragma unroll
        for (int hf = 0; hf < 2; ++hf)
            aw[hf] = *(const hv8*)(w2T + (size_t)(nbase + hf * 16 + l15) * 256 + (t << 5) + (kq << 3));
        #pragma unroll
        for (int pf = 0; pf < 4; ++pf)
            bh[pf] = *(const hv8*)(pb + (pf * 16 + l15) * PB_STR + ((t << 5) | (kq << 3)));
        __builtin_amdgcn_s_setprio(1);
        #pragma unroll
        for (int hf = 0; hf < 2; ++hf)
            #pragma unroll
            for (int pf = 0; pf < 4; ++pf)
                acc[hf][pf] = __builtin_amdgcn_mfma_f32_16x16x32_f16(aw[hf], bh[pf], acc[hf][pf], 0, 0, 0);
        __builtin_amdgcn_s_setprio(0);
    }

    __syncthreads();   // all layer-2 B-reads done
    // --- h2 = relu(acc) -> pb via b64 stores ---
    #pragma unroll
    for (int hf = 0; hf < 2; ++hf) {
        const int h0 = nbase + hf * 16 + (kq << 2);
        #pragma unroll
        for (int pf = 0; pf < 4; ++pf) {
            hv4 hw;
            #pragma unroll
            for (int r = 0; r < 4; ++r)
                hw[r] = (_Float16)fmaxf(acc[hf][pf][r], 0.0f);
            *(hv4*)(&pb[(pf * 16 + l15) * PB_STR + h0]) = hw;
        }
    }

    // --- layer-3 A fragments (waves 0-3); latency hides under barrier wait ---
    hv8 aw3[8];
    if (wv < 4) {
        #pragma unroll
        for (int t = 0; t < 8; ++t)
            aw3[t] = *(const hv8*)(w3T + l15 * 256 + (t << 5) + (kq << 3));
    }
    __syncthreads();

    // --- layer-3: wave wv (0..3) owns pixels [wv*16, wv*16+16); float4 out ---
    if (wv < 4) {
        f32x4 acc3 = (f32x4){0.f, 0.f, 0.f, 0.f};
        #pragma unroll
        for (int t = 0; t < 8; ++t) {
            const hv8 bh = *(const hv8*)(pb + ((wv << 4) + l15) * PB_STR + ((t << 5) | (kq << 3)));
            acc3 = __builtin_amdgcn_mfma_f32_16x16x32_f16(aw3[t], bh, acc3, 0, 0, 0);
        }
        if (kq == 0) {   // rows 0..3 = channels
            const int n = n0 + (wv << 4) + l15;
            const bool m = pix[n] > 0;
            const int b = n >> 16;               // H*W = 65536
            float4 o4;
            o4.x = m ? (fmaxf(acc3[0] + b3g[0], 0.f) - 1.0f) : color_bg[b * 3 + 0];
            o4.y = m ? (fmaxf(acc3[1] + b3g[1], 0.f) - 1.0f) : color_bg[b * 3 + 1];
            o4.z = m ? (fmaxf(acc3[2] + b3g[2], 0.f) - 1.0f) : color_bg[b * 3 + 2];
            o4.w = m ? 1.0f : 0.0f;
            *(float4*)(out + (size_t)n * 4) = o4;
        }
    }
}

extern "C" void kernel_launch(void* const* d_in, const int* in_sizes, int n_in,
                              void* d_out, int out_size, void* d_ws, size_t ws_size,
                              hipStream_t stream) {
    const int*   pix      = (const int*)  d_in[0];
    const float* bary     = (const float*)d_in[1];
    const int*   faces    = (const int*)  d_in[2];
    const float* feature  = (const float*)d_in[3];
    const float* shapef   = (const float*)d_in[4];
    const float* color_bg = (const float*)d_in[5];
    const float* style    = (const float*)d_in[6];
    const float* w1       = (const float*)d_in[7];
    const float* b1       = (const float*)d_in[8];
    const float* w2       = (const float*)d_in[9];
    const float* b2       = (const float*)d_in[10];
    const float* w3       = (const float*)d_in[11];
    const float* b3       = (const float*)d_in[12];
    float* out = (float*)d_out;

    const int nV = in_sizes[3] / 256;                         // 50000 vertices

    char* ws = (char*)d_ws;
    _Float16* w1T  = (_Float16*)ws;                           // 229,376 B
    _Float16* w2T  = (_Float16*)(ws + 229376);                // 131,072 B
    float*    b1p  = (float*)   (ws + 360448);                // 1,024 B
    _Float16* w3T  = (_Float16*)(ws + 361472);                // 8,192 B
    _Float16* Ptab = (_Float16*)(ws + 369664);                // nV*256*2 = 25.6 MB

    hipLaunchKernelGGL(prep_weights, dim3(513), dim3(256), 0, stream,
                       style, w1, b1, w2, w3, w1T, w2T, w3T, b1p);
    hipLaunchKernelGGL(pgemm, dim3((nV + 63) / 64), dim3(256), 0, stream,
                       feature, shapef, w1T, Ptab, nV);

    const int npix = in_sizes[0];                             // 262144
    hipLaunchKernelGGL(renderer, dim3(npix / TILE_M), dim3(512), 0, stream,
                       pix, bary, faces, Ptab, color_bg,
                       b2, b3, w1T, w2T, w3T, b1p, out);
}